// Round 9
// baseline (845.218 us; speedup 1.0000x reference)
//
#include <hip/hip_runtime.h>
#include <hip/hip_cooperative_groups.h>

namespace cg = cooperative_groups;

#define K_DIM 128
#define NTOT   125000          // 100000 + 20000 + 5000 dst rows
#define RPB    512             // rows per bucket
#define NB     245             // ceil(NTOT / RPB)
#define SRC_BITS 19            // src < 500000 < 2^19
#define SRC_MASK 0x7FFFF
#define CHUNK 4096
#define NBLK_BUILD 1024
#define GRAIN 8192

typedef __attribute__((ext_vector_type(8))) short bf16x8;           // 8 bf16 = 4 VGPR
typedef __attribute__((ext_vector_type(8))) unsigned short u16x8;   // 16 B
typedef __attribute__((ext_vector_type(4))) float f32x4;            // MFMA acc

static __device__ __forceinline__ unsigned short f2bf(float f) {
    union { float f; unsigned u; } v; v.f = f;
    unsigned r = v.u + 0x7FFF + ((v.u >> 16) & 1);   // RNE
    return (unsigned short)(r >> 16);
}
static __device__ __forceinline__ float bf2f(unsigned short b) {
    union { unsigned u; float f; } v; v.u = ((unsigned)b) << 16;
    return v.f;
}

// ---------------------------------------------------------------------------
// conv helpers (feats f32 -> bf16 plane), chunk = one uint4 of 8 bf16
// ---------------------------------------------------------------------------
static __device__ __forceinline__ void conv_one(
    const float* __restrict__ feats, unsigned short* __restrict__ fbf, long i)
{
    float4 x = reinterpret_cast<const float4*>(feats)[2 * i];
    float4 y = reinterpret_cast<const float4*>(feats)[2 * i + 1];
    uint4 o;
    o.x = (unsigned)f2bf(x.x) | ((unsigned)f2bf(x.y) << 16);
    o.y = (unsigned)f2bf(x.z) | ((unsigned)f2bf(x.w) << 16);
    o.z = (unsigned)f2bf(y.x) | ((unsigned)f2bf(y.y) << 16);
    o.w = (unsigned)f2bf(y.z) | ((unsigned)f2bf(y.w) << 16);
    reinterpret_cast<uint4*>(fbf)[i] = o;
}

// dynamic work-stealing conv: pulls GRAIN-sized chunk ranges from cursor
static __device__ void conv_pull(const float* __restrict__ feats,
                                 unsigned short* __restrict__ fbf,
                                 int lo, int hi, int* __restrict__ cursor,
                                 int* convbase_s, int t)
{
    if (hi <= lo) return;
    while (true) {
        if (t == 0) *convbase_s = atomicAdd(cursor, GRAIN);
        __syncthreads();
        int base = *convbase_s;
        __syncthreads();
        if (lo + base >= hi) break;
        int end = (lo + base + GRAIN < hi) ? (lo + base + GRAIN) : hi;
        for (int i = lo + base + t; i < end; i += 256)
            conv_one(feats, fbf, i);
    }
}

static __device__ __forceinline__ void conv_w_item(
    int idx,
    const float* __restrict__ w0s, const float* __restrict__ w0n,
    const float* __restrict__ w1s, const float* __restrict__ w1n,
    const float* __restrict__ w2s, const float* __restrict__ w2n,
    unsigned short* __restrict__ wbf)
{
    if (idx >= 81920) return;
    if (idx < 16384) {
        wbf[idx] = f2bf(w0s[idx]);
    } else if (idx < 32768) {
        int i = idx - 16384; float v = w0n[i];
        unsigned short hi = f2bf(v);
        wbf[16384 + i] = hi;
        wbf[32768 + i] = f2bf(v - bf2f(hi));
    } else if (idx < 49152) {
        int i = idx - 32768;
        wbf[49152 + i] = f2bf(w1s[i]);
    } else if (idx < 65536) {
        int i = idx - 49152; float v = w1n[i];
        unsigned short hi = f2bf(v);
        wbf[65536 + i] = hi;
        wbf[81920 + i] = f2bf(v - bf2f(hi));
    } else if (idx < 73728) {
        int i = idx - 65536;
        wbf[98304 + i] = f2bf(w2s[i]);
    } else {
        int i = idx - 73728; float v = w2n[i];
        unsigned short hi = f2bf(v);
        wbf[106496 + i] = hi;
        wbf[114688 + i] = f2bf(v - bf2f(hi));
    }
}

// ---------------------------------------------------------------------------
// Cooperative build kernel: the whole CSR build + conversions in ONE dispatch.
// Phases (grid.sync between): 0 zero-init | 1 count + conv_w + conv[0,C1) |
// 2 scan (block 0) | 3 scatter + conv[C1,C2) | 4 fill + conv[C2,CTOT).
// Conv distributed via work-stealing cursors (bcnt[250/251/252]).
// ---------------------------------------------------------------------------
struct BuildArgs {
    const int *s0, *d0, *s1, *d1, *s2, *d2;
    int E0, E1, Etot;
    int *bcnt, *bbase, *bcur, *ebuf, *rowstart, *csr;
    const float *w0s, *w0n, *w1s, *w1n, *w2s, *w2n;
    unsigned short *wbf;
    const float *feats;
    unsigned short *feats_bf;
    int C1, C2, CTOT;
};

__global__ __launch_bounds__(256)
void build_coop_kernel(BuildArgs a)
{
    cg::grid_group grid = cg::this_grid();
    __shared__ int shA[RPB];     // 512: hist
    __shared__ int shB[256];     // ps / start
    __shared__ int shC[RPB];     // 512: rst
    __shared__ int convbase;

    const int t = threadIdx.x;
    const int b = blockIdx.x;

    // ---- phase 0: zero bcnt (incl. conv cursors at [250..252])
    if (b == 0) a.bcnt[t] = 0;
    grid.sync();

    // ---- phase 1: bucket count (grid-strided) + conv_w + conv part 1
    shA[t] = 0;
    __syncthreads();
    for (int e = b * 256 + t; e < a.Etot; e += NBLK_BUILD * 256) {
        int row;
        if (e < a.E0)           row = a.d0[e];
        else if (e < a.E0 + a.E1) row = 100000 + a.d1[e - a.E0];
        else                    row = 120000 + a.d2[e - a.E0 - a.E1];
        atomicAdd(&shA[row >> 9], 1);
    }
    __syncthreads();
    if (t < NB && shA[t]) atomicAdd(&a.bcnt[t], shA[t]);
    if (b >= 1 && b < 321)
        conv_w_item((b - 1) * 256 + t, a.w0s, a.w0n, a.w1s, a.w1n, a.w2s, a.w2n, a.wbf);
    conv_pull(a.feats, a.feats_bf, 0, a.C1, &a.bcnt[250], &convbase, t);
    grid.sync();

    // ---- phase 2: scan bucket counts (block 0 only)
    if (b == 0) {
        int v = (t < NB) ? a.bcnt[t] : 0;
        shB[t] = v;
        __syncthreads();
        for (int s = 1; s < 256; s <<= 1) {
            int x = (t >= s) ? shB[t - s] : 0;
            __syncthreads();
            shB[t] += x;
            __syncthreads();
        }
        int excl = shB[t] - v;
        if (t < NB) { a.bbase[t] = excl; a.bcur[t] = excl; }
        if (t == 0) a.bbase[NB] = a.Etot;
    }
    grid.sync();

    // ---- phase 3: scatter packed (lrow<<19|src) into ebuf + conv part 2
    {
        int nchunk = (a.Etot + CHUNK - 1) / CHUNK;
        for (int ch = b; ch < nchunk; ch += NBLK_BUILD) {
            int basee = ch * CHUNK;
            shA[t] = 0;
            __syncthreads();
            #pragma unroll
            for (int i = 0; i < CHUNK / 256; ++i) {
                int e = basee + i * 256 + t;
                if (e < a.Etot) {
                    int row;
                    if (e < a.E0)             row = a.d0[e];
                    else if (e < a.E0 + a.E1) row = 100000 + a.d1[e - a.E0];
                    else                      row = 120000 + a.d2[e - a.E0 - a.E1];
                    atomicAdd(&shA[row >> 9], 1);
                }
            }
            __syncthreads();
            if (t < NB) {
                int c = shA[t];
                shB[t] = c ? atomicAdd(&a.bcur[t], c) : 0;
            }
            __syncthreads();
            shA[t] = 0;
            __syncthreads();
            #pragma unroll
            for (int i = 0; i < CHUNK / 256; ++i) {
                int e = basee + i * 256 + t;
                if (e < a.Etot) {
                    int row, src;
                    if (e < a.E0)             { row = a.d0[e];                        src = a.s0[e]; }
                    else if (e < a.E0 + a.E1) { row = 100000 + a.d1[e - a.E0];        src = a.s1[e - a.E0]; }
                    else                      { row = 120000 + a.d2[e - a.E0 - a.E1]; src = a.s2[e - a.E0 - a.E1]; }
                    int bb = row >> 9;
                    int pos = shB[bb] + atomicAdd(&shA[bb], 1);
                    a.ebuf[pos] = ((row & (RPB - 1)) << SRC_BITS) | src;
                }
            }
            __syncthreads();
        }
        conv_pull(a.feats, a.feats_bf, a.C1, a.C2, &a.bcnt[251], &convbase, t);
    }
    grid.sync();

    // ---- phase 4: per-bucket counting sort -> rowstart + csr + conv part 3
    {
        for (int bk = b; bk < NB; bk += NBLK_BUILD) {
            int e0 = a.bbase[bk], e1 = a.bbase[bk + 1];
            int row0 = bk << 9;
            int nrows = (RPB < NTOT - row0) ? RPB : (NTOT - row0);

            shA[t] = 0; shA[t + 256] = 0;
            __syncthreads();
            for (int e = e0 + t; e < e1; e += 256)
                atomicAdd(&shA[(unsigned)a.ebuf[e] >> SRC_BITS], 1);
            __syncthreads();

            int a0 = shA[2 * t], a1 = shA[2 * t + 1];
            int pv = a0 + a1;
            shB[t] = pv;
            __syncthreads();
            for (int s = 1; s < 256; s <<= 1) {
                int x = (t >= s) ? shB[t - s] : 0;
                __syncthreads();
                shB[t] += x;
                __syncthreads();
            }
            int pe = shB[t] - pv;
            shC[2 * t] = pe;
            shC[2 * t + 1] = pe + a0;
            __syncthreads();

            if (2 * t < nrows)     a.rowstart[row0 + 2 * t]     = e0 + shC[2 * t];
            if (2 * t + 1 < nrows) a.rowstart[row0 + 2 * t + 1] = e0 + shC[2 * t + 1];
            if (bk == NB - 1 && t == 0) a.rowstart[NTOT] = a.Etot;
            shA[2 * t] = shC[2 * t];
            shA[2 * t + 1] = shC[2 * t + 1];
            __syncthreads();

            for (int e = e0 + t; e < e1; e += 256) {
                unsigned p = (unsigned)a.ebuf[e];
                int off = atomicAdd(&shA[p >> SRC_BITS], 1);
                a.csr[e0 + off] = p & SRC_MASK;
            }
            __syncthreads();
        }
        conv_pull(a.feats, a.feats_bf, a.C2, a.CTOT, &a.bcnt[252], &convbase, t);
    }
}

// ---------------------------------------------------------------------------
// Gather-mean, f32 source (fallback path)
// ---------------------------------------------------------------------------
__global__ __launch_bounds__(256)
void gather_mean_f32_kernel(const float* __restrict__ h,
                            const int* __restrict__ csr,
                            const int* __restrict__ rs,
                            unsigned short* __restrict__ msgb, int n)
{
    long gid = (long)blockIdx.x * 256 + threadIdx.x;
    int g = (int)(gid >> 5);
    int lane = (int)(gid & 31);
    if (g >= n) return;

    int s0 = rs[g], s1 = rs[g + 1];
    float4 acc = make_float4(0.f, 0.f, 0.f, 0.f);
    int e = s0;
    for (; e + 4 <= s1; e += 4) {
        int i0 = csr[e], i1 = csr[e + 1], i2 = csr[e + 2], i3 = csr[e + 3];
        float4 v0 = reinterpret_cast<const float4*>(h + (long)i0 * K_DIM)[lane];
        float4 v1 = reinterpret_cast<const float4*>(h + (long)i1 * K_DIM)[lane];
        float4 v2 = reinterpret_cast<const float4*>(h + (long)i2 * K_DIM)[lane];
        float4 v3 = reinterpret_cast<const float4*>(h + (long)i3 * K_DIM)[lane];
        acc.x += (v0.x + v1.x) + (v2.x + v3.x);
        acc.y += (v0.y + v1.y) + (v2.y + v3.y);
        acc.z += (v0.z + v1.z) + (v2.z + v3.z);
        acc.w += (v0.w + v1.w) + (v2.w + v3.w);
    }
    for (; e < s1; ++e) {
        int i0 = csr[e];
        float4 v0 = reinterpret_cast<const float4*>(h + (long)i0 * K_DIM)[lane];
        acc.x += v0.x; acc.y += v0.y; acc.z += v0.z; acc.w += v0.w;
    }
    float rd = 1.0f / fmaxf((float)(s1 - s0), 1.0f);
    ushort4 o;
    o.x = f2bf(acc.x * rd); o.y = f2bf(acc.y * rd);
    o.z = f2bf(acc.z * rd); o.w = f2bf(acc.w * rd);
    reinterpret_cast<ushort4*>(msgb + (long)g * K_DIM)[lane] = o;
}

// ---------------------------------------------------------------------------
// Gather-mean, bf16 source: 16 lanes/row, 16 B loads, 8-deep MLP (proven R7/R8)
// ---------------------------------------------------------------------------
__global__ __launch_bounds__(256)
void gather_mean_bf_kernel(const unsigned short* __restrict__ hb,
                           const int* __restrict__ csr,
                           const int* __restrict__ rs,
                           unsigned short* __restrict__ msgb, int n)
{
    long gid = (long)blockIdx.x * 256 + threadIdx.x;
    int g = (int)(gid >> 4);
    int lane = (int)(gid & 15);
    if (g >= n) return;

    int s0 = rs[g], s1 = rs[g + 1];
    float a[8] = {0.f, 0.f, 0.f, 0.f, 0.f, 0.f, 0.f, 0.f};
    const unsigned short* hb_l = hb + lane * 8;

    int e = s0;
    for (; e + 8 <= s1; e += 8) {
        int idx[8];
        #pragma unroll
        for (int i = 0; i < 8; ++i) idx[i] = csr[e + i];
        #pragma unroll
        for (int i = 0; i < 8; ++i) {
            u16x8 v = *reinterpret_cast<const u16x8*>(hb_l + (long)idx[i] * K_DIM);
            #pragma unroll
            for (int j = 0; j < 8; ++j) a[j] += bf2f(v[j]);
        }
    }
    for (; e < s1; ++e) {
        u16x8 v = *reinterpret_cast<const u16x8*>(hb_l + (long)csr[e] * K_DIM);
        #pragma unroll
        for (int j = 0; j < 8; ++j) a[j] += bf2f(v[j]);
    }
    float rd = 1.0f / fmaxf((float)(s1 - s0), 1.0f);
    u16x8 o;
    #pragma unroll
    for (int j = 0; j < 8; ++j) o[j] = f2bf(a[j] * rd);
    *reinterpret_cast<u16x8*>(msgb + (long)g * K_DIM + lane * 8) = o;
}

// ---------------------------------------------------------------------------
// MFMA SAGE GEMM (proven R6-R8). f32 out written only for rows < nf32.
// ---------------------------------------------------------------------------
template<int NCOL, bool RELU, bool WRITE_BF>
__global__ __launch_bounds__(256, 3)
void sage_gemm_mfma(const float* __restrict__ h,
                    const unsigned short* __restrict__ msgb,
                    const unsigned short* __restrict__ wsb,
                    const unsigned short* __restrict__ wnh,
                    const unsigned short* __restrict__ wnl,
                    const float* __restrict__ bias,
                    float* __restrict__ out,
                    unsigned short* __restrict__ outb,
                    int n, int nf32)
{
    constexpr int NCB = NCOL / 16;
    __shared__ bf16x8 Ah[8][64];
    __shared__ bf16x8 Al[8][64];
    __shared__ bf16x8 Ms[8][64];
    __shared__ bf16x8 Bs[NCB][64];
    __shared__ bf16x8 Bh[NCB][64];
    __shared__ bf16x8 Bl[NCB][64];

    const int t    = threadIdx.x;
    const int lane = t & 63;
    const int w    = t >> 6;
    const int row0 = blockIdx.x * 128;

    f32x4 acc[2][NCB];
    #pragma unroll
    for (int rf = 0; rf < 2; ++rf)
        #pragma unroll
        for (int cb = 0; cb < NCB; ++cb)
            acc[rf][cb] = (f32x4){0.f, 0.f, 0.f, 0.f};

    const int arow   = t & 127;
    const int ah2    = t >> 7;
    const int grow_a = min(row0 + arow, n - 1);
    const int arb    = arow >> 4;

    for (int kc = 0; kc < 128; kc += 32) {
        __syncthreads();
        #pragma unroll
        for (int i = 0; i < 2; ++i) {
            int hh = ah2 * 2 + i;
            const float* src = h + (long)grow_a * 128 + kc + hh * 8;
            float4 x = *reinterpret_cast<const float4*>(src);
            float4 y = *reinterpret_cast<const float4*>(src + 4);
            float xs[8] = {x.x, x.y, x.z, x.w, y.x, y.y, y.z, y.w};
            bf16x8 hi8, lo8;
            #pragma unroll
            for (int j = 0; j < 8; ++j) {
                unsigned short hu = f2bf(xs[j]);
                hi8[j] = (short)hu;
                lo8[j] = (short)f2bf(xs[j] - bf2f(hu));
            }
            int li = hh * 16 + (arow & 15);
            Ah[arb][li] = hi8;
            Al[arb][li] = lo8;
            Ms[arb][li] = *reinterpret_cast<const bf16x8*>(
                              msgb + (long)grow_a * 128 + kc + hh * 8);
        }
        if (NCOL == 128) {
            int col = t & 127, h2 = t >> 7;
            #pragma unroll
            for (int i = 0; i < 2; ++i) {
                int hh = h2 * 2 + i;
                int li = hh * 16 + (col & 15);
                int cb = col >> 4;
                long o = (long)col * 128 + kc + hh * 8;
                Bs[cb][li] = *reinterpret_cast<const bf16x8*>(wsb + o);
                Bh[cb][li] = *reinterpret_cast<const bf16x8*>(wnh + o);
                Bl[cb][li] = *reinterpret_cast<const bf16x8*>(wnl + o);
            }
        } else {
            int col = t & 63, hh = t >> 6;
            int li = hh * 16 + (col & 15);
            int cb = col >> 4;
            long o = (long)col * 128 + kc + hh * 8;
            Bs[cb][li] = *reinterpret_cast<const bf16x8*>(wsb + o);
            Bh[cb][li] = *reinterpret_cast<const bf16x8*>(wnh + o);
            Bl[cb][li] = *reinterpret_cast<const bf16x8*>(wnl + o);
        }
        __syncthreads();

        bf16x8 a0h = Ah[2 * w][lane],     a0l = Al[2 * w][lane],     m0 = Ms[2 * w][lane];
        bf16x8 a1h = Ah[2 * w + 1][lane], a1l = Al[2 * w + 1][lane], m1 = Ms[2 * w + 1][lane];
        #pragma unroll
        for (int cb = 0; cb < NCB; ++cb) {
            bf16x8 bs = Bs[cb][lane];
            bf16x8 bh = Bh[cb][lane];
            bf16x8 bl = Bl[cb][lane];
            acc[0][cb] = __builtin_amdgcn_mfma_f32_16x16x32_bf16(a0h, bs, acc[0][cb], 0, 0, 0);
            acc[0][cb] = __builtin_amdgcn_mfma_f32_16x16x32_bf16(a0l, bs, acc[0][cb], 0, 0, 0);
            acc[0][cb] = __builtin_amdgcn_mfma_f32_16x16x32_bf16(m0,  bh, acc[0][cb], 0, 0, 0);
            acc[0][cb] = __builtin_amdgcn_mfma_f32_16x16x32_bf16(m0,  bl, acc[0][cb], 0, 0, 0);
            acc[1][cb] = __builtin_amdgcn_mfma_f32_16x16x32_bf16(a1h, bs, acc[1][cb], 0, 0, 0);
            acc[1][cb] = __builtin_amdgcn_mfma_f32_16x16x32_bf16(a1l, bs, acc[1][cb], 0, 0, 0);
            acc[1][cb] = __builtin_amdgcn_mfma_f32_16x16x32_bf16(m1,  bh, acc[1][cb], 0, 0, 0);
            acc[1][cb] = __builtin_amdgcn_mfma_f32_16x16x32_bf16(m1,  bl, acc[1][cb], 0, 0, 0);
        }
    }

    #pragma unroll
    for (int rf = 0; rf < 2; ++rf) {
        #pragma unroll
        for (int cb = 0; cb < NCB; ++cb) {
            int col = cb * 16 + (lane & 15);
            float bv = bias[col];
            #pragma unroll
            for (int r = 0; r < 4; ++r) {
                int grow = row0 + w * 32 + rf * 16 + (lane >> 4) * 4 + r;
                if (grow < n) {
                    float v = acc[rf][cb][r] + bv;
                    if (RELU) v = fmaxf(v, 0.f);
                    if (grow < nf32) out[(long)grow * NCOL + col] = v;
                    if (WRITE_BF) outb[(long)grow * NCOL + col] = f2bf(v);
                }
            }
        }
    }
}

// ---------------------------------------------------------------------------
// Host (ws layouts as R6-R8; selected by ws_size). 7 dispatches total.
// ---------------------------------------------------------------------------
extern "C" void kernel_launch(void* const* d_in, const int* in_sizes, int n_in,
                              void* d_out, int out_size, void* d_ws, size_t ws_size,
                              hipStream_t stream)
{
    const float* feats   = (const float*)d_in[0];
    const int*   src0    = (const int*)d_in[1];
    const int*   dst0    = (const int*)d_in[2];
    const int*   src1    = (const int*)d_in[3];
    const int*   dst1    = (const int*)d_in[4];
    const int*   src2    = (const int*)d_in[5];
    const int*   dst2    = (const int*)d_in[6];
    const float* Wself0  = (const float*)d_in[10];
    const float* Wneigh0 = (const float*)d_in[11];
    const float* b0      = (const float*)d_in[12];
    const float* Wself1  = (const float*)d_in[13];
    const float* Wneigh1 = (const float*)d_in[14];
    const float* b1      = (const float*)d_in[15];
    const float* Wself2  = (const float*)d_in[16];
    const float* Wneigh2 = (const float*)d_in[17];
    const float* b2      = (const float*)d_in[18];

    const int E0 = in_sizes[1];
    const int E1 = in_sizes[3];
    const int E2 = in_sizes[5];
    const int Etot = E0 + E1 + E2;
    const int N1 = 100000, N2 = 20000, N3 = 5000;

    char* base = (char*)d_ws;
    const bool bfp = ws_size >= 164500000ull;

    unsigned short* feats_bf; float* h1; unsigned short* h1b;
    float* h2; unsigned short* h2b;
    unsigned short* msgb; int* ebuf; int* csr; int* rowstart;
    int* bcnt; int* bbase; int* bcur; unsigned short* wbf;

    if (bfp) {
        feats_bf = (unsigned short*)base;                  // 128,000,000 B
        h1   = (float*)base;                               // alias post-gather-L0
        h1b  = (unsigned short*)(base + 51200000);
        h2   = (float*)(base + 76800000);
        h2b  = (unsigned short*)(base + 87040000);
        msgb = (unsigned short*)(base + 128000000);        // 25,600,000 B
        csr      = (int*)(base + 153600000);
        rowstart = (int*)(base + 163600000);
        bcnt     = (int*)(base + 164100224);
        bbase    = bcnt + 256;
        bcur     = bbase + 256;
        wbf      = (unsigned short*)(base + 164103296);
    } else {
        feats_bf = nullptr;
        h1   = (float*)base;
        h1b  = nullptr;
        h2   = (float*)(base + 51200000);
        h2b  = nullptr;
        msgb = (unsigned short*)(base + 61440000);
        csr      = (int*)(base + 87040000);
        rowstart = (int*)(base + 97040000);
        bcnt     = (int*)(base + 97540224);
        bbase    = bcnt + 256;
        bcur     = bbase + 256;
        wbf      = (unsigned short*)(base + 97543296);
    }
    ebuf = (int*)msgb;   // build-phase alias (10 MB <= 25.6 MB)

    // ---- single cooperative build dispatch
    BuildArgs ba;
    ba.s0 = src0; ba.d0 = dst0; ba.s1 = src1; ba.d1 = dst1; ba.s2 = src2; ba.d2 = dst2;
    ba.E0 = E0; ba.E1 = E1; ba.Etot = Etot;
    ba.bcnt = bcnt; ba.bbase = bbase; ba.bcur = bcur;
    ba.ebuf = ebuf; ba.rowstart = rowstart; ba.csr = csr;
    ba.w0s = Wself0; ba.w0n = Wneigh0; ba.w1s = Wself1; ba.w1n = Wneigh1;
    ba.w2s = Wself2; ba.w2n = Wneigh2; ba.wbf = wbf;
    ba.feats = feats; ba.feats_bf = feats_bf;
    if (bfp) { ba.C1 = 2500000; ba.C2 = 5500000; ba.CTOT = 8000000; }
    else     { ba.C1 = 0;       ba.C2 = 0;       ba.CTOT = 0; }

    void* params[1] = { &ba };
    hipLaunchCooperativeKernel((void*)build_coop_kernel,
                               dim3(NBLK_BUILD), dim3(256), params, 0, stream);

    if (bfp) {
        // layer 0
        gather_mean_bf_kernel<<<(N1 * 16 + 255) / 256, 256, 0, stream>>>(
            feats_bf, csr, rowstart, msgb, N1);
        sage_gemm_mfma<128, true, true><<<(N1 + 127) / 128, 256, 0, stream>>>(
            feats, msgb, wbf, wbf + 16384, wbf + 32768, b0, h1, h1b, N1, N2);
        // layer 1
        gather_mean_bf_kernel<<<(N2 * 16 + 255) / 256, 256, 0, stream>>>(
            h1b, csr, rowstart + 100000, msgb, N2);
        sage_gemm_mfma<128, true, true><<<(N2 + 127) / 128, 256, 0, stream>>>(
            h1, msgb, wbf + 49152, wbf + 65536, wbf + 81920, b1, h2, h2b, N2, N3);
        // layer 2
        gather_mean_bf_kernel<<<(N3 * 16 + 255) / 256, 256, 0, stream>>>(
            h2b, csr, rowstart + 120000, msgb, N3);
        sage_gemm_mfma<64, false, false><<<(N3 + 127) / 128, 256, 0, stream>>>(
            h2, msgb, wbf + 98304, wbf + 106496, wbf + 114688, b2,
            (float*)d_out, nullptr, N3, N3);
    } else {
        gather_mean_f32_kernel<<<(N1 * 32 + 255) / 256, 256, 0, stream>>>(
            feats, csr, rowstart, msgb, N1);
        sage_gemm_mfma<128, true, false><<<(N1 + 127) / 128, 256, 0, stream>>>(
            feats, msgb, wbf, wbf + 16384, wbf + 32768, b0, h1, nullptr, N1, N1);
        gather_mean_f32_kernel<<<(N2 * 32 + 255) / 256, 256, 0, stream>>>(
            h1, csr, rowstart + 100000, msgb, N2);
        sage_gemm_mfma<128, true, false><<<(N2 + 127) / 128, 256, 0, stream>>>(
            h1, msgb, wbf + 49152, wbf + 65536, wbf + 81920, b1, h2, nullptr, N2, N2);
        gather_mean_f32_kernel<<<(N3 * 32 + 255) / 256, 256, 0, stream>>>(
            h2, csr, rowstart + 120000, msgb, N3);
        sage_gemm_mfma<64, false, false><<<(N3 + 127) / 128, 256, 0, stream>>>(
            h2, msgb, wbf + 98304, wbf + 106496, wbf + 114688, b2,
            (float*)d_out, nullptr, N3, N3);
    }
}

// Round 10
// 339.340 us; speedup vs baseline: 2.4908x; 2.4908x over previous
//
#include <hip/hip_runtime.h>

#define K_DIM 128
#define NTOT   125000          // 100000 + 20000 + 5000 dst rows
#define RPB    512             // rows per bucket
#define NB     245             // ceil(NTOT / RPB)
#define SRC_BITS 19            // src < 500000 < 2^19
#define SRC_MASK 0x7FFFF

typedef __attribute__((ext_vector_type(8))) short bf16x8;           // 8 bf16 = 4 VGPR
typedef __attribute__((ext_vector_type(8))) unsigned short u16x8;   // 16 B
typedef __attribute__((ext_vector_type(4))) float f32x4;            // MFMA acc

static __device__ __forceinline__ unsigned short f2bf(float f) {
    union { float f; unsigned u; } v; v.f = f;
    unsigned r = v.u + 0x7FFF + ((v.u >> 16) & 1);   // RNE
    return (unsigned short)(r >> 16);
}
static __device__ __forceinline__ float bf2f(unsigned short b) {
    union { unsigned u; float f; } v; v.u = ((unsigned)b) << 16;
    return v.f;
}

// conv_feat worker: grid-strided over uint4 chunks [c0,c1), ncb blocks from b0
static __device__ __forceinline__ void conv_feat_part(
    const float* __restrict__ feats, unsigned short* __restrict__ feats_bf,
    int c0, int c1, int b0, int ncb, int b, int t)
{
    int stride = ncb * 256;
    for (long i = c0 + (long)(b - b0) * 256 + t; i < c1; i += stride) {
        float4 a = reinterpret_cast<const float4*>(feats)[2 * i];
        float4 c = reinterpret_cast<const float4*>(feats)[2 * i + 1];
        uint4 o;
        o.x = (unsigned)f2bf(a.x) | ((unsigned)f2bf(a.y) << 16);
        o.y = (unsigned)f2bf(a.z) | ((unsigned)f2bf(a.w) << 16);
        o.z = (unsigned)f2bf(c.x) | ((unsigned)f2bf(c.y) << 16);
        o.w = (unsigned)f2bf(c.z) | ((unsigned)f2bf(c.w) << 16);
        reinterpret_cast<uint4*>(feats_bf)[i] = o;
    }
}

// ---------------------------------------------------------------------------
// Stage 1: [0,512) bucket-histogram dst; [512,832) split W planes;
//          [832,832+ncv) conv_feat riders over chunks [0,c1).
// ---------------------------------------------------------------------------
__global__ __launch_bounds__(256)
void prep1_kernel(const int* __restrict__ d0, const int* __restrict__ d1,
                  const int* __restrict__ d2, int E0, int E1, int Etot,
                  int* __restrict__ bucket_cnt,
                  const float* __restrict__ w0s, const float* __restrict__ w0n,
                  const float* __restrict__ w1s, const float* __restrict__ w1n,
                  const float* __restrict__ w2s, const float* __restrict__ w2n,
                  unsigned short* __restrict__ wbf,
                  const float* __restrict__ feats,
                  unsigned short* __restrict__ feats_bf, int c1, int ncv)
{
    __shared__ int hist[256];
    int b = blockIdx.x;
    int t = threadIdx.x;

    if (b < 512) {                       // ---- bucket_count
        hist[t] = 0;
        __syncthreads();
        int stride = 512 * 256;
        for (int e = b * 256 + t; e < Etot; e += stride) {
            int row;
            if (e < E0)           row = d0[e];
            else if (e < E0 + E1) row = 100000 + d1[e - E0];
            else                  row = 120000 + d2[e - E0 - E1];
            atomicAdd(&hist[row >> 9], 1);
        }
        __syncthreads();
        if (t < NB && hist[t]) atomicAdd(&bucket_cnt[t], hist[t]);
    } else if (b < 832) {                // ---- conv_w (split planes)
        int idx = (b - 512) * 256 + t;
        if (idx >= 81920) return;
        if (idx < 16384) {
            wbf[idx] = f2bf(w0s[idx]);
        } else if (idx < 32768) {
            int i = idx - 16384; float v = w0n[i];
            unsigned short hi = f2bf(v);
            wbf[16384 + i] = hi;
            wbf[32768 + i] = f2bf(v - bf2f(hi));
        } else if (idx < 49152) {
            int i = idx - 32768;
            wbf[49152 + i] = f2bf(w1s[i]);
        } else if (idx < 65536) {
            int i = idx - 49152; float v = w1n[i];
            unsigned short hi = f2bf(v);
            wbf[65536 + i] = hi;
            wbf[81920 + i] = f2bf(v - bf2f(hi));
        } else if (idx < 73728) {
            int i = idx - 65536;
            wbf[98304 + i] = f2bf(w2s[i]);
        } else {
            int i = idx - 73728; float v = w2n[i];
            unsigned short hi = f2bf(v);
            wbf[106496 + i] = hi;
            wbf[114688 + i] = f2bf(v - bf2f(hi));
        }
    } else {                             // ---- conv_feat riders
        conv_feat_part(feats, feats_bf, 0, c1, 832, ncv, b, t);
    }
}

__global__ __launch_bounds__(256)
void bucket_scan_kernel(const int* __restrict__ bucket_cnt,
                        int* __restrict__ bucket_base,
                        int* __restrict__ bucket_cursor, int Etot)
{
    __shared__ int sm[256];
    int t = threadIdx.x;
    int v = (t < NB) ? bucket_cnt[t] : 0;
    sm[t] = v;
    __syncthreads();
    for (int s = 1; s < 256; s <<= 1) {
        int a = (t >= s) ? sm[t - s] : 0;
        __syncthreads();
        sm[t] += a;
        __syncthreads();
    }
    int excl = sm[t] - v;
    if (t < NB) { bucket_base[t] = excl; bucket_cursor[t] = excl; }
    if (t == 0) bucket_base[NB] = Etot;
}

// ---------------------------------------------------------------------------
// Stage 2: [0,SCB) scatter packed (lrow<<19|src) into bucket-ordered ebuf;
//          [SCB,SCB+ncb) conv_feat riders over [c1,c2).
// ---------------------------------------------------------------------------
#define CHUNK 4096
__global__ __launch_bounds__(256)
void scatter_conv_kernel(const int* __restrict__ s0, const int* __restrict__ d0,
                         const int* __restrict__ s1, const int* __restrict__ d1,
                         const int* __restrict__ s2, const int* __restrict__ d2,
                         int E0, int E1, int Etot,
                         int* __restrict__ bucket_cursor,
                         int* __restrict__ ebuf,
                         const float* __restrict__ feats,
                         unsigned short* __restrict__ feats_bf,
                         int c1, int c2, int SCB, int ncb)
{
    __shared__ int hist[256];
    __shared__ int start[256];
    int t = threadIdx.x;
    int b = blockIdx.x;

    if (b >= SCB) {
        conv_feat_part(feats, feats_bf, c1, c2, SCB, ncb, b, t);
        return;
    }

    int base = b * CHUNK;
    hist[t] = 0;
    __syncthreads();

    #pragma unroll
    for (int i = 0; i < CHUNK / 256; ++i) {
        int e = base + i * 256 + t;
        if (e < Etot) {
            int row;
            if (e < E0)           row = d0[e];
            else if (e < E0 + E1) row = 100000 + d1[e - E0];
            else                  row = 120000 + d2[e - E0 - E1];
            atomicAdd(&hist[row >> 9], 1);
        }
    }
    __syncthreads();
    if (t < NB) {
        int c = hist[t];
        start[t] = c ? atomicAdd(&bucket_cursor[t], c) : 0;
    }
    __syncthreads();
    hist[t] = 0;
    __syncthreads();

    #pragma unroll
    for (int i = 0; i < CHUNK / 256; ++i) {
        int e = base + i * 256 + t;
        if (e < Etot) {
            int row, src;
            if (e < E0)           { row = d0[e];                    src = s0[e]; }
            else if (e < E0 + E1) { row = 100000 + d1[e - E0];      src = s1[e - E0]; }
            else                  { row = 120000 + d2[e - E0 - E1]; src = s2[e - E0 - E1]; }
            int bb = row >> 9;
            int pos = start[bb] + atomicAdd(&hist[bb], 1);
            ebuf[pos] = ((row & (RPB - 1)) << SRC_BITS) | src;
        }
    }
}

// ---------------------------------------------------------------------------
// Stage 3: [0,NB) per-bucket counting sort -> rowstart + csr;
//          [NB,NB+ncb) conv_feat riders over [c2,ctot).
// ---------------------------------------------------------------------------
__global__ __launch_bounds__(256)
void fill_conv_kernel(const int* __restrict__ ebuf,
                      const int* __restrict__ bucket_base,
                      int* __restrict__ rowstart,
                      int* __restrict__ csr, int Etot,
                      const float* __restrict__ feats,
                      unsigned short* __restrict__ feats_bf,
                      int c2, int ctot, int ncb)
{
    __shared__ int hist[RPB];
    __shared__ int ps[256];
    __shared__ int rst[RPB];

    int t = threadIdx.x;
    int b = blockIdx.x;

    if (b >= NB) {
        conv_feat_part(feats, feats_bf, c2, ctot, NB, ncb, b, t);
        return;
    }

    int e0 = bucket_base[b], e1 = bucket_base[b + 1];
    int row0 = b << 9;
    int nrows = min(RPB, NTOT - row0);

    hist[t] = 0; hist[t + 256] = 0;
    __syncthreads();
    for (int e = e0 + t; e < e1; e += 256)
        atomicAdd(&hist[(unsigned)ebuf[e] >> SRC_BITS], 1);
    __syncthreads();

    int a0 = hist[2 * t], a1 = hist[2 * t + 1];
    int pv = a0 + a1;
    ps[t] = pv;
    __syncthreads();
    for (int s = 1; s < 256; s <<= 1) {
        int a = (t >= s) ? ps[t - s] : 0;
        __syncthreads();
        ps[t] += a;
        __syncthreads();
    }
    int pe = ps[t] - pv;
    rst[2 * t] = pe;
    rst[2 * t + 1] = pe + a0;
    __syncthreads();

    if (2 * t < nrows)     rowstart[row0 + 2 * t]     = e0 + rst[2 * t];
    if (2 * t + 1 < nrows) rowstart[row0 + 2 * t + 1] = e0 + rst[2 * t + 1];
    if (b == NB - 1 && t == 0) rowstart[NTOT] = Etot;
    hist[2 * t] = rst[2 * t];
    hist[2 * t + 1] = rst[2 * t + 1];
    __syncthreads();

    for (int e = e0 + t; e < e1; e += 256) {
        unsigned p = (unsigned)ebuf[e];
        int off = atomicAdd(&hist[p >> SRC_BITS], 1);
        csr[e0 + off] = p & SRC_MASK;
    }
}

// ---------------------------------------------------------------------------
// Gather-mean, f32 source (fallback path)
// ---------------------------------------------------------------------------
__global__ __launch_bounds__(256)
void gather_mean_f32_kernel(const float* __restrict__ h,
                            const int* __restrict__ csr,
                            const int* __restrict__ rs,
                            unsigned short* __restrict__ msgb, int n)
{
    long gid = (long)blockIdx.x * 256 + threadIdx.x;
    int g = (int)(gid >> 5);
    int lane = (int)(gid & 31);
    if (g >= n) return;

    int s0 = rs[g], s1 = rs[g + 1];
    float4 acc = make_float4(0.f, 0.f, 0.f, 0.f);
    int e = s0;
    for (; e + 4 <= s1; e += 4) {
        int i0 = csr[e], i1 = csr[e + 1], i2 = csr[e + 2], i3 = csr[e + 3];
        float4 v0 = reinterpret_cast<const float4*>(h + (long)i0 * K_DIM)[lane];
        float4 v1 = reinterpret_cast<const float4*>(h + (long)i1 * K_DIM)[lane];
        float4 v2 = reinterpret_cast<const float4*>(h + (long)i2 * K_DIM)[lane];
        float4 v3 = reinterpret_cast<const float4*>(h + (long)i3 * K_DIM)[lane];
        acc.x += (v0.x + v1.x) + (v2.x + v3.x);
        acc.y += (v0.y + v1.y) + (v2.y + v3.y);
        acc.z += (v0.z + v1.z) + (v2.z + v3.z);
        acc.w += (v0.w + v1.w) + (v2.w + v3.w);
    }
    for (; e < s1; ++e) {
        int i0 = csr[e];
        float4 v0 = reinterpret_cast<const float4*>(h + (long)i0 * K_DIM)[lane];
        acc.x += v0.x; acc.y += v0.y; acc.z += v0.z; acc.w += v0.w;
    }
    float rd = 1.0f / fmaxf((float)(s1 - s0), 1.0f);
    ushort4 o;
    o.x = f2bf(acc.x * rd); o.y = f2bf(acc.y * rd);
    o.z = f2bf(acc.z * rd); o.w = f2bf(acc.w * rd);
    reinterpret_cast<ushort4*>(msgb + (long)g * K_DIM)[lane] = o;
}

// ---------------------------------------------------------------------------
// Gather-mean, bf16 source: 16 lanes/row, 16 B loads, 8-deep MLP (proven R7/R8)
// ---------------------------------------------------------------------------
__global__ __launch_bounds__(256)
void gather_mean_bf_kernel(const unsigned short* __restrict__ hb,
                           const int* __restrict__ csr,
                           const int* __restrict__ rs,
                           unsigned short* __restrict__ msgb, int n)
{
    long gid = (long)blockIdx.x * 256 + threadIdx.x;
    int g = (int)(gid >> 4);
    int lane = (int)(gid & 15);
    if (g >= n) return;

    int s0 = rs[g], s1 = rs[g + 1];
    float a[8] = {0.f, 0.f, 0.f, 0.f, 0.f, 0.f, 0.f, 0.f};
    const unsigned short* hb_l = hb + lane * 8;

    int e = s0;
    for (; e + 8 <= s1; e += 8) {
        int idx[8];
        #pragma unroll
        for (int i = 0; i < 8; ++i) idx[i] = csr[e + i];
        #pragma unroll
        for (int i = 0; i < 8; ++i) {
            u16x8 v = *reinterpret_cast<const u16x8*>(hb_l + (long)idx[i] * K_DIM);
            #pragma unroll
            for (int j = 0; j < 8; ++j) a[j] += bf2f(v[j]);
        }
    }
    for (; e < s1; ++e) {
        u16x8 v = *reinterpret_cast<const u16x8*>(hb_l + (long)csr[e] * K_DIM);
        #pragma unroll
        for (int j = 0; j < 8; ++j) a[j] += bf2f(v[j]);
    }
    float rd = 1.0f / fmaxf((float)(s1 - s0), 1.0f);
    u16x8 o;
    #pragma unroll
    for (int j = 0; j < 8; ++j) o[j] = f2bf(a[j] * rd);
    *reinterpret_cast<u16x8*>(msgb + (long)g * K_DIM + lane * 8) = o;
}

// ---------------------------------------------------------------------------
// MFMA SAGE GEMM (proven R6-R8). f32 out written only for rows < nf32.
// ---------------------------------------------------------------------------
template<int NCOL, bool RELU, bool WRITE_BF>
__global__ __launch_bounds__(256, 3)
void sage_gemm_mfma(const float* __restrict__ h,
                    const unsigned short* __restrict__ msgb,
                    const unsigned short* __restrict__ wsb,
                    const unsigned short* __restrict__ wnh,
                    const unsigned short* __restrict__ wnl,
                    const float* __restrict__ bias,
                    float* __restrict__ out,
                    unsigned short* __restrict__ outb,
                    int n, int nf32)
{
    constexpr int NCB = NCOL / 16;
    __shared__ bf16x8 Ah[8][64];
    __shared__ bf16x8 Al[8][64];
    __shared__ bf16x8 Ms[8][64];
    __shared__ bf16x8 Bs[NCB][64];
    __shared__ bf16x8 Bh[NCB][64];
    __shared__ bf16x8 Bl[NCB][64];

    const int t    = threadIdx.x;
    const int lane = t & 63;
    const int w    = t >> 6;
    const int row0 = blockIdx.x * 128;

    f32x4 acc[2][NCB];
    #pragma unroll
    for (int rf = 0; rf < 2; ++rf)
        #pragma unroll
        for (int cb = 0; cb < NCB; ++cb)
            acc[rf][cb] = (f32x4){0.f, 0.f, 0.f, 0.f};

    const int arow   = t & 127;
    const int ah2    = t >> 7;
    const int grow_a = min(row0 + arow, n - 1);
    const int arb    = arow >> 4;

    for (int kc = 0; kc < 128; kc += 32) {
        __syncthreads();
        #pragma unroll
        for (int i = 0; i < 2; ++i) {
            int hh = ah2 * 2 + i;
            const float* src = h + (long)grow_a * 128 + kc + hh * 8;
            float4 x = *reinterpret_cast<const float4*>(src);
            float4 y = *reinterpret_cast<const float4*>(src + 4);
            float xs[8] = {x.x, x.y, x.z, x.w, y.x, y.y, y.z, y.w};
            bf16x8 hi8, lo8;
            #pragma unroll
            for (int j = 0; j < 8; ++j) {
                unsigned short hu = f2bf(xs[j]);
                hi8[j] = (short)hu;
                lo8[j] = (short)f2bf(xs[j] - bf2f(hu));
            }
            int li = hh * 16 + (arow & 15);
            Ah[arb][li] = hi8;
            Al[arb][li] = lo8;
            Ms[arb][li] = *reinterpret_cast<const bf16x8*>(
                              msgb + (long)grow_a * 128 + kc + hh * 8);
        }
        if (NCOL == 128) {
            int col = t & 127, h2 = t >> 7;
            #pragma unroll
            for (int i = 0; i < 2; ++i) {
                int hh = h2 * 2 + i;
                int li = hh * 16 + (col & 15);
                int cb = col >> 4;
                long o = (long)col * 128 + kc + hh * 8;
                Bs[cb][li] = *reinterpret_cast<const bf16x8*>(wsb + o);
                Bh[cb][li] = *reinterpret_cast<const bf16x8*>(wnh + o);
                Bl[cb][li] = *reinterpret_cast<const bf16x8*>(wnl + o);
            }
        } else {
            int col = t & 63, hh = t >> 6;
            int li = hh * 16 + (col & 15);
            int cb = col >> 4;
            long o = (long)col * 128 + kc + hh * 8;
            Bs[cb][li] = *reinterpret_cast<const bf16x8*>(wsb + o);
            Bh[cb][li] = *reinterpret_cast<const bf16x8*>(wnh + o);
            Bl[cb][li] = *reinterpret_cast<const bf16x8*>(wnl + o);
        }
        __syncthreads();

        bf16x8 a0h = Ah[2 * w][lane],     a0l = Al[2 * w][lane],     m0 = Ms[2 * w][lane];
        bf16x8 a1h = Ah[2 * w + 1][lane], a1l = Al[2 * w + 1][lane], m1 = Ms[2 * w + 1][lane];
        #pragma unroll
        for (int cb = 0; cb < NCB; ++cb) {
            bf16x8 bs = Bs[cb][lane];
            bf16x8 bh = Bh[cb][lane];
            bf16x8 bl = Bl[cb][lane];
            acc[0][cb] = __builtin_amdgcn_mfma_f32_16x16x32_bf16(a0h, bs, acc[0][cb], 0, 0, 0);
            acc[0][cb] = __builtin_amdgcn_mfma_f32_16x16x32_bf16(a0l, bs, acc[0][cb], 0, 0, 0);
            acc[0][cb] = __builtin_amdgcn_mfma_f32_16x16x32_bf16(m0,  bh, acc[0][cb], 0, 0, 0);
            acc[0][cb] = __builtin_amdgcn_mfma_f32_16x16x32_bf16(m0,  bl, acc[0][cb], 0, 0, 0);
            acc[1][cb] = __builtin_amdgcn_mfma_f32_16x16x32_bf16(a1h, bs, acc[1][cb], 0, 0, 0);
            acc[1][cb] = __builtin_amdgcn_mfma_f32_16x16x32_bf16(a1l, bs, acc[1][cb], 0, 0, 0);
            acc[1][cb] = __builtin_amdgcn_mfma_f32_16x16x32_bf16(m1,  bh, acc[1][cb], 0, 0, 0);
            acc[1][cb] = __builtin_amdgcn_mfma_f32_16x16x32_bf16(m1,  bl, acc[1][cb], 0, 0, 0);
        }
    }

    #pragma unroll
    for (int rf = 0; rf < 2; ++rf) {
        #pragma unroll
        for (int cb = 0; cb < NCB; ++cb) {
            int col = cb * 16 + (lane & 15);
            float bv = bias[col];
            #pragma unroll
            for (int r = 0; r < 4; ++r) {
                int grow = row0 + w * 32 + rf * 16 + (lane >> 4) * 4 + r;
                if (grow < n) {
                    float v = acc[rf][cb][r] + bv;
                    if (RELU) v = fmaxf(v, 0.f);
                    if (grow < nf32) out[(long)grow * NCOL + col] = v;
                    if (WRITE_BF) outb[(long)grow * NCOL + col] = f2bf(v);
                }
            }
        }
    }
}

// ---------------------------------------------------------------------------
// Host (ws layouts as R6-R8; selected by ws_size). 10 dispatches total.
// ---------------------------------------------------------------------------
extern "C" void kernel_launch(void* const* d_in, const int* in_sizes, int n_in,
                              void* d_out, int out_size, void* d_ws, size_t ws_size,
                              hipStream_t stream)
{
    const float* feats   = (const float*)d_in[0];
    const int*   src0    = (const int*)d_in[1];
    const int*   dst0    = (const int*)d_in[2];
    const int*   src1    = (const int*)d_in[3];
    const int*   dst1    = (const int*)d_in[4];
    const int*   src2    = (const int*)d_in[5];
    const int*   dst2    = (const int*)d_in[6];
    const float* Wself0  = (const float*)d_in[10];
    const float* Wneigh0 = (const float*)d_in[11];
    const float* b0      = (const float*)d_in[12];
    const float* Wself1  = (const float*)d_in[13];
    const float* Wneigh1 = (const float*)d_in[14];
    const float* b1      = (const float*)d_in[15];
    const float* Wself2  = (const float*)d_in[16];
    const float* Wneigh2 = (const float*)d_in[17];
    const float* b2      = (const float*)d_in[18];

    const int E0 = in_sizes[1];
    const int E1 = in_sizes[3];
    const int E2 = in_sizes[5];
    const int Etot = E0 + E1 + E2;
    const int N1 = 100000, N2 = 20000, N3 = 5000;

    char* base = (char*)d_ws;
    const bool bfp = ws_size >= 164500000ull;

    unsigned short* feats_bf; float* h1; unsigned short* h1b;
    float* h2; unsigned short* h2b;
    unsigned short* msgb; int* ebuf; int* csr; int* rowstart;
    int* bcnt; int* bbase; int* bcur; unsigned short* wbf;

    if (bfp) {
        feats_bf = (unsigned short*)base;                  // 128,000,000 B
        h1   = (float*)base;                               // alias post-gather-L0
        h1b  = (unsigned short*)(base + 51200000);
        h2   = (float*)(base + 76800000);
        h2b  = (unsigned short*)(base + 87040000);
        msgb = (unsigned short*)(base + 128000000);        // 25,600,000 B
        csr      = (int*)(base + 153600000);
        rowstart = (int*)(base + 163600000);
        bcnt     = (int*)(base + 164100224);
        bbase    = bcnt + 256;
        bcur     = bbase + 256;
        wbf      = (unsigned short*)(base + 164103296);
    } else {
        feats_bf = nullptr;
        h1   = (float*)base;
        h1b  = nullptr;
        h2   = (float*)(base + 51200000);
        h2b  = nullptr;
        msgb = (unsigned short*)(base + 61440000);
        csr      = (int*)(base + 87040000);
        rowstart = (int*)(base + 97040000);
        bcnt     = (int*)(base + 97540224);
        bbase    = bcnt + 256;
        bcur     = bbase + 256;
        wbf      = (unsigned short*)(base + 97543296);
    }
    ebuf = (int*)msgb;   // build-phase alias (10 MB <= 25.6 MB)

    // ---- build pipeline with conv_feat riders on all three stages
    const int SCB  = (Etot + CHUNK - 1) / CHUNK;     // scatter blocks (~611)
    const int NCV  = bfp ? 1024 : 0;                 // riders on scatter/fill
    const int NCVP = bfp ? 512  : 0;                 // riders on prep1
    const int CTOT = bfp ? 8000000 : 0;              // uint4 chunks in feats
    const int C1   = bfp ? 1500000 : 0;              // prep1 conv share
    const int C2   = bfp ? 5000000 : 0;              // scatter conv end (3.5M)

    hipMemsetAsync(bcnt, 0, 1024, stream);
    prep1_kernel<<<832 + NCVP, 256, 0, stream>>>(
        dst0, dst1, dst2, E0, E1, Etot, bcnt,
        Wself0, Wneigh0, Wself1, Wneigh1, Wself2, Wneigh2, wbf,
        feats, feats_bf, C1, NCVP);
    bucket_scan_kernel<<<1, 256, 0, stream>>>(bcnt, bbase, bcur, Etot);
    scatter_conv_kernel<<<SCB + NCV, 256, 0, stream>>>(
        src0, dst0, src1, dst1, src2, dst2, E0, E1, Etot, bcur, ebuf,
        feats, feats_bf, C1, C2, SCB, NCV);
    fill_conv_kernel<<<NB + NCV, 256, 0, stream>>>(
        ebuf, bbase, rowstart, csr, Etot, feats, feats_bf, C2, CTOT, NCV);

    if (bfp) {
        // layer 0
        gather_mean_bf_kernel<<<(N1 * 16 + 255) / 256, 256, 0, stream>>>(
            feats_bf, csr, rowstart, msgb, N1);
        sage_gemm_mfma<128, true, true><<<(N1 + 127) / 128, 256, 0, stream>>>(
            feats, msgb, wbf, wbf + 16384, wbf + 32768, b0, h1, h1b, N1, N2);
        // layer 1
        gather_mean_bf_kernel<<<(N2 * 16 + 255) / 256, 256, 0, stream>>>(
            h1b, csr, rowstart + 100000, msgb, N2);
        sage_gemm_mfma<128, true, true><<<(N2 + 127) / 128, 256, 0, stream>>>(
            h1, msgb, wbf + 49152, wbf + 65536, wbf + 81920, b1, h2, h2b, N2, N3);
        // layer 2
        gather_mean_bf_kernel<<<(N3 * 16 + 255) / 256, 256, 0, stream>>>(
            h2b, csr, rowstart + 120000, msgb, N3);
        sage_gemm_mfma<64, false, false><<<(N3 + 127) / 128, 256, 0, stream>>>(
            h2, msgb, wbf + 98304, wbf + 106496, wbf + 114688, b2,
            (float*)d_out, nullptr, N3, N3);
    } else {
        gather_mean_f32_kernel<<<(N1 * 32 + 255) / 256, 256, 0, stream>>>(
            feats, csr, rowstart, msgb, N1);
        sage_gemm_mfma<128, true, false><<<(N1 + 127) / 128, 256, 0, stream>>>(
            feats, msgb, wbf, wbf + 16384, wbf + 32768, b0, h1, nullptr, N1, N1);
        gather_mean_f32_kernel<<<(N2 * 32 + 255) / 256, 256, 0, stream>>>(
            h1, csr, rowstart + 100000, msgb, N2);
        sage_gemm_mfma<128, true, false><<<(N2 + 127) / 128, 256, 0, stream>>>(
            h1, msgb, wbf + 49152, wbf + 65536, wbf + 81920, b1, h2, nullptr, N2, N2);
        gather_mean_f32_kernel<<<(N3 * 32 + 255) / 256, 256, 0, stream>>>(
            h2, csr, rowstart + 120000, msgb, N3);
        sage_gemm_mfma<64, false, false><<<(N3 + 127) / 128, 256, 0, stream>>>(
            h2, msgb, wbf + 98304, wbf + 106496, wbf + 114688, b2,
            (float*)d_out, nullptr, N3, N3);
    }
}

// Round 11
// 334.542 us; speedup vs baseline: 2.5265x; 1.0143x over previous
//
#include <hip/hip_runtime.h>

#define K_DIM 128
#define NTOT   125000          // 100000 + 20000 + 5000 dst rows
#define RPB    512             // rows per bucket
#define NB     245             // ceil(NTOT / RPB)
#define CAP    12288           // static per-bucket capacity (expected ~10240)
#define SRC_BITS 19            // src < 500000 < 2^19
#define SRC_MASK 0x7FFFF
#define CHUNK 4096

typedef __attribute__((ext_vector_type(8))) short bf16x8;           // 8 bf16 = 4 VGPR
typedef __attribute__((ext_vector_type(8))) unsigned short u16x8;   // 16 B
typedef __attribute__((ext_vector_type(4))) float f32x4;            // MFMA acc

static __device__ __forceinline__ unsigned short f2bf(float f) {
    union { float f; unsigned u; } v; v.f = f;
    unsigned r = v.u + 0x7FFF + ((v.u >> 16) & 1);   // RNE
    return (unsigned short)(r >> 16);
}
static __device__ __forceinline__ float bf2f(unsigned short b) {
    union { unsigned u; float f; } v; v.u = ((unsigned)b) << 16;
    return v.f;
}

// conv_feat worker: grid-strided over uint4 chunks [c0,c1), ncb blocks from b0
static __device__ __forceinline__ void conv_feat_part(
    const float* __restrict__ feats, unsigned short* __restrict__ feats_bf,
    int c0, int c1, int b0, int ncb, int b, int t)
{
    int stride = ncb * 256;
    for (long i = c0 + (long)(b - b0) * 256 + t; i < c1; i += stride) {
        float4 a = reinterpret_cast<const float4*>(feats)[2 * i];
        float4 c = reinterpret_cast<const float4*>(feats)[2 * i + 1];
        uint4 o;
        o.x = (unsigned)f2bf(a.x) | ((unsigned)f2bf(a.y) << 16);
        o.y = (unsigned)f2bf(a.z) | ((unsigned)f2bf(a.w) << 16);
        o.z = (unsigned)f2bf(c.x) | ((unsigned)f2bf(c.y) << 16);
        o.w = (unsigned)f2bf(c.z) | ((unsigned)f2bf(c.w) << 16);
        reinterpret_cast<uint4*>(feats_bf)[i] = o;
    }
}

static __device__ __forceinline__ void conv_w_item(
    int idx,
    const float* __restrict__ w0s, const float* __restrict__ w0n,
    const float* __restrict__ w1s, const float* __restrict__ w1n,
    const float* __restrict__ w2s, const float* __restrict__ w2n,
    unsigned short* __restrict__ wbf)
{
    if (idx >= 81920) return;
    if (idx < 16384) {
        wbf[idx] = f2bf(w0s[idx]);
    } else if (idx < 32768) {
        int i = idx - 16384; float v = w0n[i];
        unsigned short hi = f2bf(v);
        wbf[16384 + i] = hi;
        wbf[32768 + i] = f2bf(v - bf2f(hi));
    } else if (idx < 49152) {
        int i = idx - 32768;
        wbf[49152 + i] = f2bf(w1s[i]);
    } else if (idx < 65536) {
        int i = idx - 49152; float v = w1n[i];
        unsigned short hi = f2bf(v);
        wbf[65536 + i] = hi;
        wbf[81920 + i] = f2bf(v - bf2f(hi));
    } else if (idx < 73728) {
        int i = idx - 65536;
        wbf[98304 + i] = f2bf(w2s[i]);
    } else {
        int i = idx - 73728; float v = w2n[i];
        unsigned short hi = f2bf(v);
        wbf[106496 + i] = hi;
        wbf[114688 + i] = f2bf(v - bf2f(hi));
    }
}

// ---------------------------------------------------------------------------
// Stage 1: [0,SCB) scatter packed (lrow<<19|src) into STATIC bucket regions
// (base = b*CAP + atomic cursor; no count/scan passes needed);
// [SCB,SCB+320) conv_w; [SCB+320,+ncv) conv_feat riders over [0,c2).
// ---------------------------------------------------------------------------
__global__ __launch_bounds__(256)
void scatter_static_kernel(const int* __restrict__ s0, const int* __restrict__ d0,
                           const int* __restrict__ s1, const int* __restrict__ d1,
                           const int* __restrict__ s2, const int* __restrict__ d2,
                           int E0, int E1, int Etot,
                           int* __restrict__ bcur,
                           int* __restrict__ ebuf,
                           const float* __restrict__ w0s, const float* __restrict__ w0n,
                           const float* __restrict__ w1s, const float* __restrict__ w1n,
                           const float* __restrict__ w2s, const float* __restrict__ w2n,
                           unsigned short* __restrict__ wbf,
                           const float* __restrict__ feats,
                           unsigned short* __restrict__ feats_bf,
                           int c2, int SCB, int ncv)
{
    __shared__ int hist[256];
    __shared__ int start[256];
    int t = threadIdx.x;
    int b = blockIdx.x;

    if (b >= SCB + 320) {                // ---- conv_feat riders
        conv_feat_part(feats, feats_bf, 0, c2, SCB + 320, ncv, b, t);
        return;
    }
    if (b >= SCB) {                      // ---- conv_w
        conv_w_item((b - SCB) * 256 + t, w0s, w0n, w1s, w1n, w2s, w2n, wbf);
        return;
    }

    int base = b * CHUNK;
    hist[t] = 0;
    __syncthreads();

    #pragma unroll
    for (int i = 0; i < CHUNK / 256; ++i) {
        int e = base + i * 256 + t;
        if (e < Etot) {
            int row;
            if (e < E0)           row = d0[e];
            else if (e < E0 + E1) row = 100000 + d1[e - E0];
            else                  row = 120000 + d2[e - E0 - E1];
            atomicAdd(&hist[row >> 9], 1);
        }
    }
    __syncthreads();
    if (t < NB) {
        int c = hist[t];
        start[t] = c ? (t * CAP + atomicAdd(&bcur[t], c)) : 0;
    }
    __syncthreads();
    hist[t] = 0;
    __syncthreads();

    #pragma unroll
    for (int i = 0; i < CHUNK / 256; ++i) {
        int e = base + i * 256 + t;
        if (e < Etot) {
            int row, src;
            if (e < E0)           { row = d0[e];                    src = s0[e]; }
            else if (e < E0 + E1) { row = 100000 + d1[e - E0];      src = s1[e - E0]; }
            else                  { row = 120000 + d2[e - E0 - E1]; src = s2[e - E0 - E1]; }
            int bb = row >> 9;
            int pos = start[bb] + atomicAdd(&hist[bb], 1);
            if (pos < (bb + 1) * CAP)    // overflow guard (never fires; no OOB)
                ebuf[pos] = ((row & (RPB - 1)) << SRC_BITS) | src;
        }
    }
}

// ---------------------------------------------------------------------------
// Stage 2: [0,NB) per-bucket counting sort -> rse (per-row start/end) + csr;
// [NB,NB+ncv) conv_feat riders over [c2,ctot).
// ---------------------------------------------------------------------------
__global__ __launch_bounds__(256)
void fill_static_kernel(const int* __restrict__ ebuf,
                        const int* __restrict__ bcur,
                        int2* __restrict__ rse,
                        int* __restrict__ csr,
                        const float* __restrict__ feats,
                        unsigned short* __restrict__ feats_bf,
                        int c2, int ctot, int ncv)
{
    __shared__ int hist[RPB];
    __shared__ int ps[256];
    __shared__ int rst[RPB];

    int t = threadIdx.x;
    int b = blockIdx.x;

    if (b >= NB) {                       // ---- conv_feat riders
        conv_feat_part(feats, feats_bf, c2, ctot, NB, ncv, b, t);
        return;
    }

    int e0 = b * CAP;
    int cnt = min(bcur[b], CAP);
    int row0 = b << 9;
    int nrows = min(RPB, NTOT - row0);

    hist[t] = 0; hist[t + 256] = 0;
    __syncthreads();
    for (int e = e0 + t; e < e0 + cnt; e += 256)
        atomicAdd(&hist[(unsigned)ebuf[e] >> SRC_BITS], 1);
    __syncthreads();

    int a0 = hist[2 * t], a1 = hist[2 * t + 1];
    int pv = a0 + a1;
    ps[t] = pv;
    __syncthreads();
    for (int s = 1; s < 256; s <<= 1) {
        int a = (t >= s) ? ps[t - s] : 0;
        __syncthreads();
        ps[t] += a;
        __syncthreads();
    }
    int pe = ps[t] - pv;
    rst[2 * t] = pe;
    rst[2 * t + 1] = pe + a0;
    __syncthreads();

    if (2 * t < nrows)
        rse[row0 + 2 * t]     = make_int2(e0 + pe, e0 + pe + a0);
    if (2 * t + 1 < nrows)
        rse[row0 + 2 * t + 1] = make_int2(e0 + pe + a0, e0 + pe + a0 + a1);
    hist[2 * t] = rst[2 * t];
    hist[2 * t + 1] = rst[2 * t + 1];
    __syncthreads();

    for (int e = e0 + t; e < e0 + cnt; e += 256) {
        unsigned p = (unsigned)ebuf[e];
        int off = atomicAdd(&hist[p >> SRC_BITS], 1);
        csr[e0 + off] = p & SRC_MASK;
    }
}

// ---------------------------------------------------------------------------
// Gather-mean, f32 source (fallback path)
// ---------------------------------------------------------------------------
__global__ __launch_bounds__(256)
void gather_mean_f32_kernel(const float* __restrict__ h,
                            const int* __restrict__ csr,
                            const int2* __restrict__ rse,
                            unsigned short* __restrict__ msgb, int n)
{
    long gid = (long)blockIdx.x * 256 + threadIdx.x;
    int g = (int)(gid >> 5);
    int lane = (int)(gid & 31);
    if (g >= n) return;

    int2 se = rse[g];
    int s0 = se.x, s1 = se.y;
    float4 acc = make_float4(0.f, 0.f, 0.f, 0.f);
    int e = s0;
    for (; e + 4 <= s1; e += 4) {
        int i0 = csr[e], i1 = csr[e + 1], i2 = csr[e + 2], i3 = csr[e + 3];
        float4 v0 = reinterpret_cast<const float4*>(h + (long)i0 * K_DIM)[lane];
        float4 v1 = reinterpret_cast<const float4*>(h + (long)i1 * K_DIM)[lane];
        float4 v2 = reinterpret_cast<const float4*>(h + (long)i2 * K_DIM)[lane];
        float4 v3 = reinterpret_cast<const float4*>(h + (long)i3 * K_DIM)[lane];
        acc.x += (v0.x + v1.x) + (v2.x + v3.x);
        acc.y += (v0.y + v1.y) + (v2.y + v3.y);
        acc.z += (v0.z + v1.z) + (v2.z + v3.z);
        acc.w += (v0.w + v1.w) + (v2.w + v3.w);
    }
    for (; e < s1; ++e) {
        int i0 = csr[e];
        float4 v0 = reinterpret_cast<const float4*>(h + (long)i0 * K_DIM)[lane];
        acc.x += v0.x; acc.y += v0.y; acc.z += v0.z; acc.w += v0.w;
    }
    float rd = 1.0f / fmaxf((float)(s1 - s0), 1.0f);
    ushort4 o;
    o.x = f2bf(acc.x * rd); o.y = f2bf(acc.y * rd);
    o.z = f2bf(acc.z * rd); o.w = f2bf(acc.w * rd);
    reinterpret_cast<ushort4*>(msgb + (long)g * K_DIM)[lane] = o;
}

// ---------------------------------------------------------------------------
// Gather-mean, bf16 source: 16 lanes/row, 16 B loads, 8-deep MLP (proven R7-R10)
// ---------------------------------------------------------------------------
__global__ __launch_bounds__(256)
void gather_mean_bf_kernel(const unsigned short* __restrict__ hb,
                           const int* __restrict__ csr,
                           const int2* __restrict__ rse,
                           unsigned short* __restrict__ msgb, int n)
{
    long gid = (long)blockIdx.x * 256 + threadIdx.x;
    int g = (int)(gid >> 4);
    int lane = (int)(gid & 15);
    if (g >= n) return;

    int2 se = rse[g];
    int s0 = se.x, s1 = se.y;
    float a[8] = {0.f, 0.f, 0.f, 0.f, 0.f, 0.f, 0.f, 0.f};
    const unsigned short* hb_l = hb + lane * 8;

    int e = s0;
    for (; e + 8 <= s1; e += 8) {
        int idx[8];
        #pragma unroll
        for (int i = 0; i < 8; ++i) idx[i] = csr[e + i];
        #pragma unroll
        for (int i = 0; i < 8; ++i) {
            u16x8 v = *reinterpret_cast<const u16x8*>(hb_l + (long)idx[i] * K_DIM);
            #pragma unroll
            for (int j = 0; j < 8; ++j) a[j] += bf2f(v[j]);
        }
    }
    for (; e < s1; ++e) {
        u16x8 v = *reinterpret_cast<const u16x8*>(hb_l + (long)csr[e] * K_DIM);
        #pragma unroll
        for (int j = 0; j < 8; ++j) a[j] += bf2f(v[j]);
    }
    float rd = 1.0f / fmaxf((float)(s1 - s0), 1.0f);
    u16x8 o;
    #pragma unroll
    for (int j = 0; j < 8; ++j) o[j] = f2bf(a[j] * rd);
    *reinterpret_cast<u16x8*>(msgb + (long)g * K_DIM + lane * 8) = o;
}

// ---------------------------------------------------------------------------
// MFMA SAGE GEMM (proven R6-R10). f32 out written only for rows < nf32.
// ---------------------------------------------------------------------------
template<int NCOL, bool RELU, bool WRITE_BF>
__global__ __launch_bounds__(256, 3)
void sage_gemm_mfma(const float* __restrict__ h,
                    const unsigned short* __restrict__ msgb,
                    const unsigned short* __restrict__ wsb,
                    const unsigned short* __restrict__ wnh,
                    const unsigned short* __restrict__ wnl,
                    const float* __restrict__ bias,
                    float* __restrict__ out,
                    unsigned short* __restrict__ outb,
                    int n, int nf32)
{
    constexpr int NCB = NCOL / 16;
    __shared__ bf16x8 Ah[8][64];
    __shared__ bf16x8 Al[8][64];
    __shared__ bf16x8 Ms[8][64];
    __shared__ bf16x8 Bs[NCB][64];
    __shared__ bf16x8 Bh[NCB][64];
    __shared__ bf16x8 Bl[NCB][64];

    const int t    = threadIdx.x;
    const int lane = t & 63;
    const int w    = t >> 6;
    const int row0 = blockIdx.x * 128;

    f32x4 acc[2][NCB];
    #pragma unroll
    for (int rf = 0; rf < 2; ++rf)
        #pragma unroll
        for (int cb = 0; cb < NCB; ++cb)
            acc[rf][cb] = (f32x4){0.f, 0.f, 0.f, 0.f};

    const int arow   = t & 127;
    const int ah2    = t >> 7;
    const int grow_a = min(row0 + arow, n - 1);
    const int arb    = arow >> 4;

    for (int kc = 0; kc < 128; kc += 32) {
        __syncthreads();
        #pragma unroll
        for (int i = 0; i < 2; ++i) {
            int hh = ah2 * 2 + i;
            const float* src = h + (long)grow_a * 128 + kc + hh * 8;
            float4 x = *reinterpret_cast<const float4*>(src);
            float4 y = *reinterpret_cast<const float4*>(src + 4);
            float xs[8] = {x.x, x.y, x.z, x.w, y.x, y.y, y.z, y.w};
            bf16x8 hi8, lo8;
            #pragma unroll
            for (int j = 0; j < 8; ++j) {
                unsigned short hu = f2bf(xs[j]);
                hi8[j] = (short)hu;
                lo8[j] = (short)f2bf(xs[j] - bf2f(hu));
            }
            int li = hh * 16 + (arow & 15);
            Ah[arb][li] = hi8;
            Al[arb][li] = lo8;
            Ms[arb][li] = *reinterpret_cast<const bf16x8*>(
                              msgb + (long)grow_a * 128 + kc + hh * 8);
        }
        if (NCOL == 128) {
            int col = t & 127, h2 = t >> 7;
            #pragma unroll
            for (int i = 0; i < 2; ++i) {
                int hh = h2 * 2 + i;
                int li = hh * 16 + (col & 15);
                int cb = col >> 4;
                long o = (long)col * 128 + kc + hh * 8;
                Bs[cb][li] = *reinterpret_cast<const bf16x8*>(wsb + o);
                Bh[cb][li] = *reinterpret_cast<const bf16x8*>(wnh + o);
                Bl[cb][li] = *reinterpret_cast<const bf16x8*>(wnl + o);
            }
        } else {
            int col = t & 63, hh = t >> 6;
            int li = hh * 16 + (col & 15);
            int cb = col >> 4;
            long o = (long)col * 128 + kc + hh * 8;
            Bs[cb][li] = *reinterpret_cast<const bf16x8*>(wsb + o);
            Bh[cb][li] = *reinterpret_cast<const bf16x8*>(wnh + o);
            Bl[cb][li] = *reinterpret_cast<const bf16x8*>(wnl + o);
        }
        __syncthreads();

        bf16x8 a0h = Ah[2 * w][lane],     a0l = Al[2 * w][lane],     m0 = Ms[2 * w][lane];
        bf16x8 a1h = Ah[2 * w + 1][lane], a1l = Al[2 * w + 1][lane], m1 = Ms[2 * w + 1][lane];
        #pragma unroll
        for (int cb = 0; cb < NCB; ++cb) {
            bf16x8 bs = Bs[cb][lane];
            bf16x8 bh = Bh[cb][lane];
            bf16x8 bl = Bl[cb][lane];
            acc[0][cb] = __builtin_amdgcn_mfma_f32_16x16x32_bf16(a0h, bs, acc[0][cb], 0, 0, 0);
            acc[0][cb] = __builtin_amdgcn_mfma_f32_16x16x32_bf16(a0l, bs, acc[0][cb], 0, 0, 0);
            acc[0][cb] = __builtin_amdgcn_mfma_f32_16x16x32_bf16(m0,  bh, acc[0][cb], 0, 0, 0);
            acc[0][cb] = __builtin_amdgcn_mfma_f32_16x16x32_bf16(m0,  bl, acc[0][cb], 0, 0, 0);
            acc[1][cb] = __builtin_amdgcn_mfma_f32_16x16x32_bf16(a1h, bs, acc[1][cb], 0, 0, 0);
            acc[1][cb] = __builtin_amdgcn_mfma_f32_16x16x32_bf16(a1l, bs, acc[1][cb], 0, 0, 0);
            acc[1][cb] = __builtin_amdgcn_mfma_f32_16x16x32_bf16(m1,  bh, acc[1][cb], 0, 0, 0);
            acc[1][cb] = __builtin_amdgcn_mfma_f32_16x16x32_bf16(m1,  bl, acc[1][cb], 0, 0, 0);
        }
    }

    #pragma unroll
    for (int rf = 0; rf < 2; ++rf) {
        #pragma unroll
        for (int cb = 0; cb < NCB; ++cb) {
            int col = cb * 16 + (lane & 15);
            float bv = bias[col];
            #pragma unroll
            for (int r = 0; r < 4; ++r) {
                int grow = row0 + w * 32 + rf * 16 + (lane >> 4) * 4 + r;
                if (grow < n) {
                    float v = acc[rf][cb][r] + bv;
                    if (RELU) v = fmaxf(v, 0.f);
                    if (grow < nf32) out[(long)grow * NCOL + col] = v;
                    if (WRITE_BF) outb[(long)grow * NCOL + col] = f2bf(v);
                }
            }
        }
    }
}

// ---------------------------------------------------------------------------
// Host. 9 dispatches. Layout (bf path, bytes):
//   feats_bf@0 (128M; aliased post-gather0 by h1@0 / h1b@51.2M / h2@76.8M /
//   h2b@87.04M), msgb@128M (25.6M, ebuf alias 12.04M), csr@153.6M (12.04M),
//   rse@165.642M (1.0M), bcur@166.642M, wbf@166.643M.  Total ~166.9 MB.
// ---------------------------------------------------------------------------
extern "C" void kernel_launch(void* const* d_in, const int* in_sizes, int n_in,
                              void* d_out, int out_size, void* d_ws, size_t ws_size,
                              hipStream_t stream)
{
    const float* feats   = (const float*)d_in[0];
    const int*   src0    = (const int*)d_in[1];
    const int*   dst0    = (const int*)d_in[2];
    const int*   src1    = (const int*)d_in[3];
    const int*   dst1    = (const int*)d_in[4];
    const int*   src2    = (const int*)d_in[5];
    const int*   dst2    = (const int*)d_in[6];
    const float* Wself0  = (const float*)d_in[10];
    const float* Wneigh0 = (const float*)d_in[11];
    const float* b0      = (const float*)d_in[12];
    const float* Wself1  = (const float*)d_in[13];
    const float* Wneigh1 = (const float*)d_in[14];
    const float* b1      = (const float*)d_in[15];
    const float* Wself2  = (const float*)d_in[16];
    const float* Wneigh2 = (const float*)d_in[17];
    const float* b2      = (const float*)d_in[18];

    const int E0 = in_sizes[1];
    const int E1 = in_sizes[3];
    const int E2 = in_sizes[5];
    const int Etot = E0 + E1 + E2;
    const int N1 = 100000, N2 = 20000, N3 = 5000;

    char* base = (char*)d_ws;
    const bool bfp = ws_size >= 167000000ull;

    unsigned short* feats_bf; float* h1; unsigned short* h1b;
    float* h2; unsigned short* h2b;
    unsigned short* msgb; int* ebuf; int* csr; int2* rse;
    int* bcur; unsigned short* wbf;

    if (bfp) {
        feats_bf = (unsigned short*)base;                  // 128,000,000 B
        h1   = (float*)base;                               // alias post-gather-L0
        h1b  = (unsigned short*)(base + 51200000);
        h2   = (float*)(base + 76800000);
        h2b  = (unsigned short*)(base + 87040000);
        msgb = (unsigned short*)(base + 128000000);        // 25,600,000 B
        csr  = (int*)(base + 153600000);                   // 12,042,240 B
        rse  = (int2*)(base + 165642240);                  //  1,000,008 B
        bcur = (int*)(base + 166642248);                   //        980 B
        wbf  = (unsigned short*)(base + 166643232);        //    245,760 B
    } else {
        feats_bf = nullptr;
        h1   = (float*)base;                               // 51,200,000 B
        h1b  = nullptr;
        h2   = (float*)(base + 51200000);                  // 10,240,000 B
        h2b  = nullptr;
        msgb = (unsigned short*)(base + 61440000);         // 25,600,000 B
        csr  = (int*)(base + 87040000);
        rse  = (int2*)(base + 99082240);
        bcur = (int*)(base + 100082248);
        wbf  = (unsigned short*)(base + 100083232);
    }
    ebuf = (int*)msgb;   // build-phase alias (12.04 MB <= 25.6 MB)

    // ---- build: static-capacity buckets, no count/scan passes
    const int SCB  = (Etot + CHUNK - 1) / CHUNK;     // ~611 scatter blocks
    const int NCV  = bfp ? 1024 : 0;                 // conv riders per stage
    const int CTOT = bfp ? 8000000 : 0;              // uint4 chunks in feats
    const int C2   = bfp ? 4200000 : 0;              // scatter conv share

    hipMemsetAsync(bcur, 0, NB * sizeof(int), stream);
    scatter_static_kernel<<<SCB + 320 + NCV, 256, 0, stream>>>(
        src0, dst0, src1, dst1, src2, dst2, E0, E1, Etot, bcur, ebuf,
        Wself0, Wneigh0, Wself1, Wneigh1, Wself2, Wneigh2, wbf,
        feats, feats_bf, C2, SCB, NCV);
    fill_static_kernel<<<NB + NCV, 256, 0, stream>>>(
        ebuf, bcur, rse, csr, feats, feats_bf, C2, CTOT, NCV);

    if (bfp) {
        // layer 0
        gather_mean_bf_kernel<<<(N1 * 16 + 255) / 256, 256, 0, stream>>>(
            feats_bf, csr, rse, msgb, N1);
        sage_gemm_mfma<128, true, true><<<(N1 + 127) / 128, 256, 0, stream>>>(
            feats, msgb, wbf, wbf + 16384, wbf + 32768, b0, h1, h1b, N1, N2);
        // layer 1
        gather_mean_bf_kernel<<<(N2 * 16 + 255) / 256, 256, 0, stream>>>(
            h1b, csr, rse + 100000, msgb, N2);
        sage_gemm_mfma<128, true, true><<<(N2 + 127) / 128, 256, 0, stream>>>(
            h1, msgb, wbf + 49152, wbf + 65536, wbf + 81920, b1, h2, h2b, N2, N3);
        // layer 2
        gather_mean_bf_kernel<<<(N3 * 16 + 255) / 256, 256, 0, stream>>>(
            h2b, csr, rse + 120000, msgb, N3);
        sage_gemm_mfma<64, false, false><<<(N3 + 127) / 128, 256, 0, stream>>>(
            h2, msgb, wbf + 98304, wbf + 106496, wbf + 114688, b2,
            (float*)d_out, nullptr, N3, N3);
    } else {
        gather_mean_f32_kernel<<<(N1 * 32 + 255) / 256, 256, 0, stream>>>(
            feats, csr, rse, msgb, N1);
        sage_gemm_mfma<128, true, false><<<(N1 + 127) / 128, 256, 0, stream>>>(
            feats, msgb, wbf, wbf + 16384, wbf + 32768, b0, h1, nullptr, N1, N1);
        gather_mean_f32_kernel<<<(N2 * 32 + 255) / 256, 256, 0, stream>>>(
            h1, csr, rse + 100000, msgb, N2);
        sage_gemm_mfma<128, true, false><<<(N2 + 127) / 128, 256, 0, stream>>>(
            h1, msgb, wbf + 49152, wbf + 65536, wbf + 81920, b1, h2, nullptr, N2, N2);
        gather_mean_f32_kernel<<<(N3 * 32 + 255) / 256, 256, 0, stream>>>(
            h2, csr, rse + 120000, msgb, N3);
        sage_gemm_mfma<64, false, false><<<(N3 + 127) / 128, 256, 0, stream>>>(
            h2, msgb, wbf + 98304, wbf + 106496, wbf + 114688, b2,
            (float*)d_out, nullptr, N3, N3);
    }
}